// Round 8
// baseline (176.305 us; speedup 1.0000x reference)
//
#include <hip/hip_runtime.h>
#include <hip/hip_bf16.h>

// GraphEncoder: the entire edge/message/update pipeline in the reference is
// dead code (update() output is discarded; h is only ever scaled per-node by
// pooling scores). Live computation:
//   a_n = relu(x_n @ W1 + b1)                       (128-dim, per node)
//   d_{n,k} = a_n . (W2 @ w_k/||w_k||) + b2.(w_k/||w_k||)   k=0..2
//   cascade: s = tanh(c * d_k) on alive nodes, top-k per graph (1024/512/256),
//            c *= s on survivors
//   out_g = ((sum_sel c_n a_n) @ W2 + (sum c_n) b2) / 256
//
// R8: k1 back to LDS-broadcast weights (R7's per-thread global W1 loads were
// the regression) + 2 nodes/thread to halve LDS reads per node. k2: keys and
// staged d-values moved ENTIRELY to registers (every sweep index maps to the
// same thread across phases -> sKey/d1A/d2A arrays deleted), and the epilogue
// x-gather turned into a one-shot parallel prefetch into LDS (one float4 per
// thread) instead of 32 serial latency-bound broadcast loads per group.
// Selection remains bit-identical to the sort formulation.

#define NPG    2048
#define NGRAPH 32
#define HP     2112
#define HPAD(b) ((b) + ((b) >> 5))   // pad: bin -> slot, kills bank aliasing

__device__ __forceinline__ unsigned int mono_bits(float z) {
    unsigned int bb = __float_as_uint(z);
    return (bb & 0x80000000u) ? ~bb : (bb | 0x80000000u);
}
__device__ __forceinline__ float mono_decode(unsigned int mo) {
    unsigned int bb = (mo & 0x80000000u) ? (mo & 0x7FFFFFFFu) : ~mo;
    return __uint_as_float(bb);
}

__global__ __launch_bounds__(256) void k1_fused(
    const float* __restrict__ x,    // [65536][16]
    const float* __restrict__ W1,   // [16][128]
    const float* __restrict__ b1,   // [128]
    const float* __restrict__ W2,   // [128][128]
    const float* __restrict__ b2,   // [128]
    const float* __restrict__ pw,   // pool_w [3][128]
    float4* __restrict__ d4)        // [65536] {d0,d1,d2,_}
{
    __shared__ float4 sW1v[512];                 // W1 as [16][32] float4
    __shared__ float4 sb1v[32];                  // b1
    __shared__ __align__(16) float swn[384];     // normalized pool_w
    __shared__ __align__(16) float sv[384];      // v_k[j] = W2 @ wn_k
    __shared__ float sc[4];                      // c_k = b2 . wn_k
    __shared__ float snorm[3];
    int t = threadIdx.x;
    int lane = t & 63, wv = t >> 6;

    for (int i = t; i < 512; i += 256) sW1v[i] = ((const float4*)W1)[i];
    if (t < 32) sb1v[t] = ((const float4*)b1)[t];
    if (wv < 3) {
        float w0 = pw[wv * 128 + lane];
        float w1 = pw[wv * 128 + 64 + lane];
        float p = w0 * w0 + w1 * w1;
        #pragma unroll
        for (int s = 32; s; s >>= 1) p += __shfl_xor(p, s);
        if (lane == 0) snorm[wv] = sqrtf(p);
    }
    __syncthreads();
    for (int i = t; i < 384; i += 256) swn[i] = pw[i] / snorm[i >> 7];
    __syncthreads();
    // 387 tasks: (k,j) dots of length 128; j==128 -> c_k = b2 . wn_k
    for (int task = t; task < 387; task += 256) {
        int k = task / 129, j = task % 129;
        const float4* r4 = (const float4*)((j < 128) ? (W2 + j * 128) : b2);
        const float* wn = swn + k * 128;
        float p0 = 0.f, p1 = 0.f, p2 = 0.f, p3 = 0.f;
        #pragma unroll 8
        for (int q = 0; q < 32; ++q) {
            float4 w = r4[q];
            p0 = fmaf(w.x, wn[4 * q + 0], p0);
            p1 = fmaf(w.y, wn[4 * q + 1], p1);
            p2 = fmaf(w.z, wn[4 * q + 2], p2);
            p3 = fmaf(w.w, wn[4 * q + 3], p3);
        }
        float p = (p0 + p1) + (p2 + p3);
        if (j < 128) sv[k * 128 + j] = p;
        else sc[k] = p;
    }
    __syncthreads();

    // two nodes per thread: every broadcast weight read serves both nodes
    int n0 = blockIdx.x * 512 + t;
    int n1 = n0 + 256;
    const float4* xr0 = (const float4*)(x + (size_t)n0 * 16);
    const float4* xr1 = (const float4*)(x + (size_t)n1 * 16);
    float4 xa = xr0[0], xb = xr0[1], xc = xr0[2], xd = xr0[3];
    float4 ya = xr1[0], yb = xr1[1], yc = xr1[2], yd = xr1[3];
    float xs[16] = {xa.x, xa.y, xa.z, xa.w, xb.x, xb.y, xb.z, xb.w,
                    xc.x, xc.y, xc.z, xc.w, xd.x, xd.y, xd.z, xd.w};
    float ys[16] = {ya.x, ya.y, ya.z, ya.w, yb.x, yb.y, yb.z, yb.w,
                    yc.x, yc.y, yc.z, yc.w, yd.x, yd.y, yd.z, yd.w};
    const float4* sv4 = (const float4*)sv;
    float d00 = sc[0], d01 = sc[1], d02 = sc[2];
    float d10 = sc[0], d11 = sc[1], d12 = sc[2];
    #pragma unroll 4
    for (int fq = 0; fq < 32; ++fq) {
        float4 bb = sb1v[fq];
        float4 a4 = bb, c4 = bb;
        #pragma unroll
        for (int j = 0; j < 16; ++j) {
            float4 w = sW1v[j * 32 + fq];
            a4.x = fmaf(xs[j], w.x, a4.x);
            a4.y = fmaf(xs[j], w.y, a4.y);
            a4.z = fmaf(xs[j], w.z, a4.z);
            a4.w = fmaf(xs[j], w.w, a4.w);
            c4.x = fmaf(ys[j], w.x, c4.x);
            c4.y = fmaf(ys[j], w.y, c4.y);
            c4.z = fmaf(ys[j], w.z, c4.z);
            c4.w = fmaf(ys[j], w.w, c4.w);
        }
        a4.x = fmaxf(a4.x, 0.f); a4.y = fmaxf(a4.y, 0.f);
        a4.z = fmaxf(a4.z, 0.f); a4.w = fmaxf(a4.w, 0.f);
        c4.x = fmaxf(c4.x, 0.f); c4.y = fmaxf(c4.y, 0.f);
        c4.z = fmaxf(c4.z, 0.f); c4.w = fmaxf(c4.w, 0.f);
        float4 v0 = sv4[fq], v1 = sv4[32 + fq], v2 = sv4[64 + fq];
        d00 = fmaf(a4.x, v0.x, fmaf(a4.y, v0.y, fmaf(a4.z, v0.z, fmaf(a4.w, v0.w, d00))));
        d01 = fmaf(a4.x, v1.x, fmaf(a4.y, v1.y, fmaf(a4.z, v1.z, fmaf(a4.w, v1.w, d01))));
        d02 = fmaf(a4.x, v2.x, fmaf(a4.y, v2.y, fmaf(a4.z, v2.z, fmaf(a4.w, v2.w, d02))));
        d10 = fmaf(c4.x, v0.x, fmaf(c4.y, v0.y, fmaf(c4.z, v0.z, fmaf(c4.w, v0.w, d10))));
        d11 = fmaf(c4.x, v1.x, fmaf(c4.y, v1.y, fmaf(c4.z, v1.z, fmaf(c4.w, v1.w, d11))));
        d12 = fmaf(c4.x, v2.x, fmaf(c4.y, v2.y, fmaf(c4.z, v2.z, fmaf(c4.w, v2.w, d12))));
    }
    d4[n0] = make_float4(d00, d01, d02, 0.f);
    d4[n1] = make_float4(d10, d11, d12, 0.f);
}

// one block per graph. Keys/staged d live in REGISTERS (index m == thread t
// identity across phases); LDS only holds histograms, compacted survivor
// arrays, weights, and the epilogue gather buffer.
__global__ __launch_bounds__(1024, 1) void k2_cascade(
    const float* __restrict__ x,
    const float* __restrict__ W1,
    const float* __restrict__ b1,
    const float* __restrict__ W2,
    const float* __restrict__ b2,
    const float4* __restrict__ d4,
    float* __restrict__ out)        // [32][128]
{
    __shared__ unsigned int hist[2][HP];
    __shared__ int   idxB[1024];
    __shared__ float cscB[1024], d1B[1024], d2B[1024];
    __shared__ int   idxA2[512];
    __shared__ float cscA2[512], d2A2[512];
    __shared__ float sW1[2048], sb1[128];
    __shared__ float4 xg[256][4];               // prefetched selected x rows
    __shared__ float Spart[1024], Svec[128], red4[4];
    __shared__ unsigned long long sPrefix;
    __shared__ int sNeed, sDone, sCnt;

    int t = threadIdx.x, g = blockIdx.x;
    int lane = t & 63, wv = t >> 6;
    const float4* d4g = d4 + (size_t)g * NPG;

    // issue d-loads first; HBM latency hides under the zero/stage phase
    float4 e0 = d4g[t];
    float4 e1 = d4g[t + 1024];
    for (int i = t; i < 2048; i += 1024) sW1[i] = W1[i];
    if (t < 128) sb1[t] = b1[t];
    for (int i = t; i < 2 * HP; i += 1024) ((unsigned int*)hist)[i] = 0u;
    if (t == 0) { sPrefix = 0ull; sNeed = 1024; sDone = 0; sCnt = 0; }
    __syncthreads();

    // key = mono(z)<<11 | (2047-n): desc == (score desc, idx asc), exactly
    // lax.top_k order; tanh monotone -> rank by z = c*d directly.
    unsigned long long kv0 = ((unsigned long long)mono_bits(e0.x) << 11)
                           | (unsigned long long)(unsigned int)(2047 - t);
    unsigned long long kv1 = ((unsigned long long)mono_bits(e1.x) << 11)
                           | (unsigned long long)(unsigned int)(1023 - t);
    atomicAdd(&hist[0][HPAD((unsigned int)(kv0 >> 33) & 2047u)], 1u);
    atomicAdd(&hist[0][HPAD((unsigned int)(kv1 >> 33) & 2047u)], 1u);
    __syncthreads();

    // ---------------- shared radix-scan lambda (wave 0) -------------------
    auto scan_pass = [&](int buf, int shift, int pass) {
        if (wv == 0) {   // lane L owns bins [32L, 32L+32)
            unsigned long long pref = sPrefix;
            unsigned int need = (unsigned int)sNeed;
            unsigned int h[32], tl = 0;
            #pragma unroll
            for (int b = 0; b < 32; ++b) {
                h[b] = hist[buf][HPAD(32u * t + b)];
                tl += h[b];
            }
            unsigned int s = tl;   // inclusive suffix-sum across lanes
            #pragma unroll
            for (int d = 1; d < 64; d <<= 1) {
                unsigned int v = __shfl_down(s, d);
                if (t + d < 64) s += v;
            }
            unsigned int above = s - tl;   // sum over lanes > L
            if (above < need && above + tl >= need) {   // unique owner
                unsigned int cum = above;
                #pragma unroll
                for (int b = 31; b >= 0; --b) {
                    cum += h[b];
                    if (cum >= need) {
                        int nn = (int)(need - (cum - h[b]));
                        sNeed = nn;
                        sPrefix = pref |
                            ((unsigned long long)(unsigned int)(32 * t + b) << shift);
                        // early exit: boundary bucket fully selected
                        sDone = (nn == (int)h[b]) || (pass == 3);
                        break;
                    }
                }
            }
        }
    };

    // ---------------- round 0: N=2048, k=1024, keys kv0/kv1 ---------------
    {
        int lastBuf = 0;
        for (int pass = 0; pass < 4; ++pass) {
            int buf = pass & 1;
            int shift = 33 - 11 * pass;
            lastBuf = buf;
            if (pass > 0) {
                unsigned long long pref = sPrefix;
                if ((kv0 >> (shift + 11)) == (pref >> (shift + 11)))
                    atomicAdd(&hist[buf][HPAD((unsigned int)(kv0 >> shift) & 2047u)], 1u);
                if ((kv1 >> (shift + 11)) == (pref >> (shift + 11)))
                    atomicAdd(&hist[buf][HPAD((unsigned int)(kv1 >> shift) & 2047u)], 1u);
                __syncthreads();
            }
            scan_pass(buf, shift, pass);
            if (wv != 0 && pass > 0)
                for (int i = t - 64; i < HP; i += 960) hist[buf ^ 1][i] = 0u;
            __syncthreads();
            if (sDone) break;
        }
        unsigned long long thr = sPrefix;
        for (int i = t; i < HP; i += 1024) hist[lastBuf][i] = 0u;
        #pragma unroll
        for (int half = 0; half < 2; ++half) {
            unsigned long long kv = half ? kv1 : kv0;
            float dy = half ? e1.y : e0.y;
            float dz = half ? e1.z : e0.z;
            bool pred = (kv >= thr);   // keys distinct -> exactly 1024 selected
            unsigned long long mask = __ballot(pred);
            if (mask) {
                int leader = __ffsll((long long)mask) - 1;
                int base = 0;
                if (lane == leader) base = atomicAdd(&sCnt, __popcll(mask));
                base = __shfl(base, leader);
                if (pred) {
                    int pos = base + __popcll(mask & ((1ull << lane) - 1ull));
                    float z = mono_decode((unsigned int)(kv >> 11)); // exact z
                    idxB[pos] = 2047 - (int)((unsigned int)kv & 2047u);
                    cscB[pos] = tanhf(z);
                    d1B[pos] = dy; d2B[pos] = dz;
                }
            }
        }
        __syncthreads();
    }

    // ---------------- round 1: N=1024, k=512, key in register -------------
    {
        if (t == 0) { sPrefix = 0ull; sNeed = 512; sDone = 0; sCnt = 0; }
        float ci = cscB[t], dv = d1B[t], d2r = d2B[t];
        int ni = idxB[t];
        float z = ci * dv;
        unsigned long long kv = ((unsigned long long)mono_bits(z) << 11)
                              | (unsigned long long)(unsigned int)(2047 - ni);
        __syncthreads();   // reset visible before scan; keygen reads done
        atomicAdd(&hist[0][HPAD((unsigned int)(kv >> 33) & 2047u)], 1u);
        __syncthreads();
        int lastBuf = 0;
        for (int pass = 0; pass < 4; ++pass) {
            int buf = pass & 1;
            int shift = 33 - 11 * pass;
            lastBuf = buf;
            if (pass > 0) {
                unsigned long long pref = sPrefix;
                if ((kv >> (shift + 11)) == (pref >> (shift + 11)))
                    atomicAdd(&hist[buf][HPAD((unsigned int)(kv >> shift) & 2047u)], 1u);
                __syncthreads();
            }
            scan_pass(buf, shift, pass);
            if (wv != 0 && pass > 0)
                for (int i = t - 64; i < HP; i += 960) hist[buf ^ 1][i] = 0u;
            __syncthreads();
            if (sDone) break;
        }
        unsigned long long thr = sPrefix;
        for (int i = t; i < HP; i += 1024) hist[lastBuf][i] = 0u;
        bool pred = (kv >= thr);
        unsigned long long mask = __ballot(pred);
        if (mask) {
            int leader = __ffsll((long long)mask) - 1;
            int base = 0;
            if (lane == leader) base = atomicAdd(&sCnt, __popcll(mask));
            base = __shfl(base, leader);
            if (pred) {
                int pos = base + __popcll(mask & ((1ull << lane) - 1ull));
                float zz = mono_decode((unsigned int)(kv >> 11));
                idxA2[pos] = ni;
                cscA2[pos] = ci * tanhf(zz);
                d2A2[pos] = d2r;
            }
        }
        __syncthreads();
    }

    // ---------------- round 2: N=512, k=256, key in register --------------
    {
        if (t == 0) { sPrefix = 0ull; sNeed = 256; sDone = 0; sCnt = 0; }
        float ci = 0.f; int ni = 0;
        unsigned long long kv = 0ull;
        if (t < 512) {
            ci = cscA2[t]; ni = idxA2[t];
            float z = ci * d2A2[t];
            kv = ((unsigned long long)mono_bits(z) << 11)
               | (unsigned long long)(unsigned int)(2047 - ni);
        }
        __syncthreads();
        if (t < 512)
            atomicAdd(&hist[0][HPAD((unsigned int)(kv >> 33) & 2047u)], 1u);
        __syncthreads();
        int lastBuf = 0;
        for (int pass = 0; pass < 4; ++pass) {
            int buf = pass & 1;
            int shift = 33 - 11 * pass;
            lastBuf = buf;
            if (pass > 0) {
                unsigned long long pref = sPrefix;
                if (t < 512 &&
                    (kv >> (shift + 11)) == (pref >> (shift + 11)))
                    atomicAdd(&hist[buf][HPAD((unsigned int)(kv >> shift) & 2047u)], 1u);
                __syncthreads();
            }
            scan_pass(buf, shift, pass);
            if (wv != 0 && pass > 0)
                for (int i = t - 64; i < HP; i += 960) hist[buf ^ 1][i] = 0u;
            __syncthreads();
            if (sDone) break;
        }
        unsigned long long thr = sPrefix;
        if (t < 512) {   // waves 0..7 only; full-wave ballot within them
            bool pred = (kv >= thr);
            unsigned long long mask = __ballot(pred);
            if (mask) {
                int leader = __ffsll((long long)mask) - 1;
                int base = 0;
                if (lane == leader) base = atomicAdd(&sCnt, __popcll(mask));
                base = __shfl(base, leader);
                if (pred) {
                    int pos = base + __popcll(mask & ((1ull << lane) - 1ull));
                    float zz = mono_decode((unsigned int)(kv >> 11));
                    idxB[pos] = ni;
                    cscB[pos] = ci * tanhf(zz);
                }
            }
        }
        __syncthreads();
    }

    // ---------------- epilogue ----------------
    // parallel x-prefetch: thread t loads float4 #(t&3) of selected row t>>2
    {
        int i = t >> 2, j = t & 3;
        const float4* xr = (const float4*)(x + (size_t)(g * NPG + idxB[i]) * 16);
        xg[i][j] = xr[j];
    }
    __syncthreads();
    // S[f] = sum_{sel} c_n * relu(x_n @ W1 + b1)[f]
    {
        int f = t & 127, grp = t >> 7;
        float Sacc = 0.f;
        #pragma unroll 2
        for (int it = grp; it < 256; it += 8) {
            float cn = cscB[it];
            float4 xa = xg[it][0], xb = xg[it][1], xc = xg[it][2], xd = xg[it][3];
            float acc = sb1[f];
            acc = fmaf(xa.x, sW1[0 * 128 + f], acc);
            acc = fmaf(xa.y, sW1[1 * 128 + f], acc);
            acc = fmaf(xa.z, sW1[2 * 128 + f], acc);
            acc = fmaf(xa.w, sW1[3 * 128 + f], acc);
            acc = fmaf(xb.x, sW1[4 * 128 + f], acc);
            acc = fmaf(xb.y, sW1[5 * 128 + f], acc);
            acc = fmaf(xb.z, sW1[6 * 128 + f], acc);
            acc = fmaf(xb.w, sW1[7 * 128 + f], acc);
            acc = fmaf(xc.x, sW1[8 * 128 + f], acc);
            acc = fmaf(xc.y, sW1[9 * 128 + f], acc);
            acc = fmaf(xc.z, sW1[10 * 128 + f], acc);
            acc = fmaf(xc.w, sW1[11 * 128 + f], acc);
            acc = fmaf(xd.x, sW1[12 * 128 + f], acc);
            acc = fmaf(xd.y, sW1[13 * 128 + f], acc);
            acc = fmaf(xd.z, sW1[14 * 128 + f], acc);
            acc = fmaf(xd.w, sW1[15 * 128 + f], acc);
            Sacc += fmaxf(acc, 0.f) * cn;
        }
        Spart[t] = Sacc;
    }
    if (t < 256) {   // Csum = sum_{sel} c_n
        float cpart = cscB[t];
        #pragma unroll
        for (int s = 32; s; s >>= 1) cpart += __shfl_xor(cpart, s);
        if ((t & 63) == 0) red4[t >> 6] = cpart;
    }
    __syncthreads();
    if (t < 128) {
        float sv = 0.f;
        #pragma unroll
        for (int h = 0; h < 8; ++h) sv += Spart[h * 128 + t];
        Svec[t] = sv;
    }
    __syncthreads();
    {   // GEMV: all 16 waves; group jc handles j in [16*jc, 16*jc+16)
        int f = t & 127, jc = t >> 7;
        float part = 0.f;
        #pragma unroll
        for (int j = 16 * jc; j < 16 * jc + 16; ++j)
            part = fmaf(Svec[j], W2[j * 128 + f], part);
        Spart[t] = part;
    }
    __syncthreads();
    if (t < 128) {
        float Csum = (red4[0] + red4[1]) + (red4[2] + red4[3]);
        float acc = Csum * b2[t];
        #pragma unroll
        for (int h = 0; h < 8; ++h) acc += Spart[h * 128 + t];
        out[g * 128 + t] = acc * (1.0f / 256.0f);
    }
}

extern "C" void kernel_launch(void* const* d_in, const int* in_sizes, int n_in,
                              void* d_out, int out_size, void* d_ws, size_t ws_size,
                              hipStream_t stream) {
    const float* x  = (const float*)d_in[0];
    const float* W1 = (const float*)d_in[2];   // node_w1 [16][128]
    const float* b1 = (const float*)d_in[3];   // node_b1 [128]
    const float* W2 = (const float*)d_in[4];   // node_w2 [128][128]
    const float* b2 = (const float*)d_in[5];   // node_b2 [128]
    const float* pw = (const float*)d_in[22];  // pool_w  [3][128]
    float* out = (float*)d_out;

    float4* d4 = (float4*)d_ws;   // [65536] float4 = 1 MB

    k1_fused<<<128, 256, 0, stream>>>(x, W1, b1, W2, b2, pw, d4);
    k2_cascade<<<NGRAPH, 1024, 0, stream>>>(x, W1, b1, W2, b2, d4, out);
}

// Round 9
// 170.398 us; speedup vs baseline: 1.0347x; 1.0347x over previous
//
#include <hip/hip_runtime.h>
#include <hip/hip_bf16.h>

// GraphEncoder: the entire edge/message/update pipeline in the reference is
// dead code (update() output is discarded; h is only ever scaled per-node by
// pooling scores). Live computation:
//   a_n = relu(x_n @ W1 + b1)                       (128-dim, per node)
//   d_{n,k} = a_n . (W2 @ w_k/||w_k||) + b2.(w_k/||w_k||)   k=0..2
//   cascade: s = tanh(c * d_k) on alive nodes, top-k per graph (1024/512/256),
//            c *= s on survivors
//   out_g = ((sum_sel c_n a_n) @ W2 + (sum c_n) b2) / 256
//
// R9: CONTROLLED A/B — exact resubmit of the R5 kernel (best measured,
// 168.2 us). R6/R7/R8 (three structurally different k2 rewrites) all landed
// at 175.6-176.3, a +/-0.4us band; this run discriminates "R5 was favorable
// noise" vs "R6-R8 all regressed k2". No edits vs R5.

#define NPG    2048
#define NGRAPH 32
#define HP     2112
#define HPAD(b) ((b) + ((b) >> 5))   // pad: bin -> slot, kills bank aliasing

__global__ __launch_bounds__(256) void k1_fused(
    const float* __restrict__ x,    // [65536][16]
    const float* __restrict__ W1,   // [16][128]
    const float* __restrict__ b1,   // [128]
    const float* __restrict__ W2,   // [128][128]
    const float* __restrict__ b2,   // [128]
    const float* __restrict__ pw,   // pool_w [3][128]
    float4* __restrict__ d4)        // [65536] {d0,d1,d2,_}
{
    __shared__ float4 sW1v[512];                 // W1 as [16][32] float4
    __shared__ float4 sb1v[32];                  // b1
    __shared__ __align__(16) float swn[384];     // normalized pool_w
    __shared__ __align__(16) float sv[384];      // v_k[j] = W2 @ wn_k
    __shared__ float sc[4];                      // c_k = b2 . wn_k
    __shared__ float snorm[3];
    int t = threadIdx.x;
    int lane = t & 63, wv = t >> 6;

    for (int i = t; i < 512; i += 256) sW1v[i] = ((const float4*)W1)[i];
    if (t < 32) sb1v[t] = ((const float4*)b1)[t];
    if (wv < 3) {
        float w0 = pw[wv * 128 + lane];
        float w1 = pw[wv * 128 + 64 + lane];
        float p = w0 * w0 + w1 * w1;
        #pragma unroll
        for (int s = 32; s; s >>= 1) p += __shfl_xor(p, s);
        if (lane == 0) snorm[wv] = sqrtf(p);
    }
    __syncthreads();
    for (int i = t; i < 384; i += 256) swn[i] = pw[i] / snorm[i >> 7];
    __syncthreads();
    // 387 tasks: (k,j) dots of length 128; j==128 -> c_k = b2 . wn_k
    for (int task = t; task < 387; task += 256) {
        int k = task / 129, j = task % 129;
        const float4* r4 = (const float4*)((j < 128) ? (W2 + j * 128) : b2);
        const float* wn = swn + k * 128;
        float p0 = 0.f, p1 = 0.f, p2 = 0.f, p3 = 0.f;
        #pragma unroll 8
        for (int q = 0; q < 32; ++q) {
            float4 w = r4[q];
            p0 = fmaf(w.x, wn[4 * q + 0], p0);
            p1 = fmaf(w.y, wn[4 * q + 1], p1);
            p2 = fmaf(w.z, wn[4 * q + 2], p2);
            p3 = fmaf(w.w, wn[4 * q + 3], p3);
        }
        float p = (p0 + p1) + (p2 + p3);
        if (j < 128) sv[k * 128 + j] = p;
        else sc[k] = p;
    }
    __syncthreads();

    // one node per thread, everything broadcast from LDS
    int n = blockIdx.x * 256 + t;
    const float4* xr = (const float4*)(x + (size_t)n * 16);
    float4 xa = xr[0], xb = xr[1], xc = xr[2], xd = xr[3];
    float xs[16] = {xa.x, xa.y, xa.z, xa.w, xb.x, xb.y, xb.z, xb.w,
                    xc.x, xc.y, xc.z, xc.w, xd.x, xd.y, xd.z, xd.w};
    const float4* sv4 = (const float4*)sv;
    float dd0 = sc[0], dd1 = sc[1], dd2 = sc[2];
    #pragma unroll 4
    for (int fq = 0; fq < 32; ++fq) {
        float4 a4 = sb1v[fq];
        #pragma unroll
        for (int j = 0; j < 16; ++j) {
            float4 w = sW1v[j * 32 + fq];
            a4.x = fmaf(xs[j], w.x, a4.x);
            a4.y = fmaf(xs[j], w.y, a4.y);
            a4.z = fmaf(xs[j], w.z, a4.z);
            a4.w = fmaf(xs[j], w.w, a4.w);
        }
        a4.x = fmaxf(a4.x, 0.f); a4.y = fmaxf(a4.y, 0.f);
        a4.z = fmaxf(a4.z, 0.f); a4.w = fmaxf(a4.w, 0.f);
        float4 v0 = sv4[fq], v1 = sv4[32 + fq], v2 = sv4[64 + fq];
        dd0 = fmaf(a4.x, v0.x, fmaf(a4.y, v0.y, fmaf(a4.z, v0.z, fmaf(a4.w, v0.w, dd0))));
        dd1 = fmaf(a4.x, v1.x, fmaf(a4.y, v1.y, fmaf(a4.z, v1.z, fmaf(a4.w, v1.w, dd1))));
        dd2 = fmaf(a4.x, v2.x, fmaf(a4.y, v2.y, fmaf(a4.z, v2.z, fmaf(a4.w, v2.w, dd2))));
    }
    d4[n] = make_float4(dd0, dd1, dd2, 0.f);
}

// one block per graph: 3x (fused keygen/hist0 + early-exit radix + ballot
// compaction) + final gather-GEMV
__global__ __launch_bounds__(1024, 1) void k2_cascade(
    const float* __restrict__ x,
    const float* __restrict__ W1,
    const float* __restrict__ b1,
    const float* __restrict__ W2,
    const float* __restrict__ b2,
    const float4* __restrict__ d4,
    float* __restrict__ out)        // [32][128]
{
    __shared__ float d0A[NPG], d1A[NPG], d2A[NPG];
    __shared__ unsigned long long sKey[NPG];
    __shared__ unsigned int hist[2][HP];
    __shared__ int   idxB[1024];
    __shared__ float cscB[1024], d1B[1024], d2B[1024];
    __shared__ int   idxA2[512];
    __shared__ float cscA2[512], d2A2[512];
    __shared__ float sW1[2048], sb1[128];
    __shared__ float Spart[1024], Svec[128], red4[4];
    __shared__ unsigned long long sPrefix;
    __shared__ int sNeed, sDone, sCnt;

    int t = threadIdx.x, g = blockIdx.x;
    int lane = t & 63, wv = t >> 6;

    for (int n = t; n < NPG; n += 1024) {
        float4 dd = d4[g * NPG + n];
        d0A[n] = dd.x; d1A[n] = dd.y; d2A[n] = dd.z;
    }
    for (int i = t; i < 2048; i += 1024) sW1[i] = W1[i];
    if (t < 128) sb1[t] = b1[t];
    for (int i = t; i < 2 * HP; i += 1024) ((unsigned int*)hist)[i] = 0u;
    __syncthreads();

    int curN = NPG;
    for (int r = 0; r < 3; ++r) {
        int kk = 1024 >> r;
        const float* dIn   = (r == 0) ? d0A : (r == 1) ? d1B : d2A2;
        const float* cscIn = (r == 0) ? (const float*)0 : (r == 1) ? cscB : cscA2;
        const int*   idxIn = (r == 0) ? (const int*)0 : (r == 1) ? idxB : idxA2;
        int*   idxOut = (r == 1) ? idxA2 : idxB;
        float* cscOut = (r == 1) ? cscA2 : cscB;

        if (t == 0) { sPrefix = 0ull; sNeed = kk; sDone = 0; sCnt = 0; }
        // keygen + pass-0 histogram fused (key stays in register for hist0).
        // key = mono(z)<<11 | (2047-n): desc == (score desc, idx asc), the
        // exact lax.top_k order; tanh monotone -> rank by z = c*d directly.
        for (int m = t; m < curN; m += 1024) {
            float ci = cscIn ? cscIn[m] : 1.f;
            int   ni = idxIn ? idxIn[m] : m;
            float z = ci * dIn[m];
            unsigned int bb = __float_as_uint(z);
            unsigned int mo = (bb & 0x80000000u) ? ~bb : (bb | 0x80000000u);
            unsigned long long kv = ((unsigned long long)mo << 11)
                                  | (unsigned long long)(unsigned int)(2047 - ni);
            sKey[m] = kv;
            atomicAdd(&hist[0][HPAD((unsigned int)(kv >> 33) & 2047u)], 1u);
        }
        __syncthreads();

        int lastBuf = 0;
        for (int pass = 0; pass < 4; ++pass) {
            int buf = pass & 1;
            int shift = 33 - 11 * pass;
            lastBuf = buf;
            if (pass > 0) {  // histogram candidates under current prefix
                unsigned long long pref = sPrefix;
                for (int m = t; m < curN; m += 1024) {
                    unsigned long long kv = sKey[m];
                    if ((kv >> (shift + 11)) == (pref >> (shift + 11)))
                        atomicAdd(&hist[buf][HPAD((unsigned int)(kv >> shift) & 2047u)], 1u);
                }
                __syncthreads();
            }
            if (wv == 0) {   // wave 0: scan 2048 bins, lane L owns [32L,32L+32)
                unsigned long long pref = sPrefix;
                unsigned int need = (unsigned int)sNeed;
                unsigned int h[32], tl = 0;
                #pragma unroll
                for (int b = 0; b < 32; ++b) {
                    h[b] = hist[buf][HPAD(32u * t + b)];
                    tl += h[b];
                }
                unsigned int s = tl;   // inclusive suffix-sum across lanes
                #pragma unroll
                for (int d = 1; d < 64; d <<= 1) {
                    unsigned int v = __shfl_down(s, d);
                    if (t + d < 64) s += v;
                }
                unsigned int above = s - tl;   // sum over lanes > L
                if (above < need && above + tl >= need) {   // unique owner
                    unsigned int cum = above;
                    #pragma unroll
                    for (int b = 31; b >= 0; --b) {
                        cum += h[b];
                        if (cum >= need) {
                            int nn = (int)(need - (cum - h[b]));
                            sNeed = nn;
                            sPrefix = pref |
                                ((unsigned long long)(unsigned int)(32 * t + b) << shift);
                            // early exit: whole boundary bucket selected ->
                            // thr = prefix (low bits 0) picks exactly kk keys
                            sDone = (nn == (int)h[b]) || (pass == 3);
                            break;
                        }
                    }
                }
            } else if (pass > 0) {
                // waves 1..15: zero the other buffer (used by previous pass,
                // needed zero by the next one) while wave 0 scans
                for (int i = t - 64; i < HP; i += 960) hist[buf ^ 1][i] = 0u;
            }
            __syncthreads();
            if (sDone) break;
        }
        unsigned long long thr = sPrefix;

        // compaction (ballot-aggregated: one LDS atomic per wave-iteration)
        // + zero the one still-dirty hist buffer for the next round
        for (int i = t; i < HP; i += 1024) hist[lastBuf][i] = 0u;
        for (int m = t; m < curN; m += 1024) {
            unsigned long long kv = sKey[m];
            bool pred = (kv >= thr);   // keys distinct -> exactly kk selected
            unsigned long long mask = __ballot(pred);
            if (mask) {
                int leader = __ffsll((long long)mask) - 1;
                int cnt = __popcll(mask);
                int base = 0;
                if (lane == leader) base = atomicAdd(&sCnt, cnt);
                base = __shfl(base, leader);
                if (pred) {
                    int rank = __popcll(mask & ((1ull << lane) - 1ull));
                    int pos = base + rank;
                    float ci = cscIn ? cscIn[m] : 1.f;
                    int   ni = idxIn ? idxIn[m] : m;
                    float z = ci * dIn[m];
                    idxOut[pos] = ni;
                    cscOut[pos] = ci * tanhf(z);   // tanh only for survivors
                    if (r == 0)      { d1B[pos] = d1A[m]; d2B[pos] = d2A[m]; }
                    else if (r == 1) { d2A2[pos] = d2B[m]; }
                }
            }
        }
        __syncthreads();
        curN = kk;
    }

    // S[f] = sum_{sel} c_n * relu(x_n @ W1 + b1)[f]; sel/csc in idxB/cscB[0..256)
    {
        int f = t & 127, grp = t >> 7;
        float Sacc = 0.f;
        #pragma unroll 2
        for (int it = grp; it < 256; it += 8) {
            int n = idxB[it];
            float cn = cscB[it];
            const float4* xr = (const float4*)(x + (size_t)(g * NPG + n) * 16);
            float4 xa = xr[0], xb = xr[1], xc = xr[2], xd = xr[3];
            float acc = sb1[f];
            acc = fmaf(xa.x, sW1[0 * 128 + f], acc);
            acc = fmaf(xa.y, sW1[1 * 128 + f], acc);
            acc = fmaf(xa.z, sW1[2 * 128 + f], acc);
            acc = fmaf(xa.w, sW1[3 * 128 + f], acc);
            acc = fmaf(xb.x, sW1[4 * 128 + f], acc);
            acc = fmaf(xb.y, sW1[5 * 128 + f], acc);
            acc = fmaf(xb.z, sW1[6 * 128 + f], acc);
            acc = fmaf(xb.w, sW1[7 * 128 + f], acc);
            acc = fmaf(xc.x, sW1[8 * 128 + f], acc);
            acc = fmaf(xc.y, sW1[9 * 128 + f], acc);
            acc = fmaf(xc.z, sW1[10 * 128 + f], acc);
            acc = fmaf(xc.w, sW1[11 * 128 + f], acc);
            acc = fmaf(xd.x, sW1[12 * 128 + f], acc);
            acc = fmaf(xd.y, sW1[13 * 128 + f], acc);
            acc = fmaf(xd.z, sW1[14 * 128 + f], acc);
            acc = fmaf(xd.w, sW1[15 * 128 + f], acc);
            Sacc += fmaxf(acc, 0.f) * cn;
        }
        Spart[t] = Sacc;
    }
    if (t < 256) {   // Csum = sum_{sel} c_n
        float cpart = cscB[t];
        #pragma unroll
        for (int s = 32; s; s >>= 1) cpart += __shfl_xor(cpart, s);
        if ((t & 63) == 0) red4[t >> 6] = cpart;
    }
    __syncthreads();
    if (t < 128) {
        float sv = 0.f;
        #pragma unroll
        for (int h = 0; h < 8; ++h) sv += Spart[h * 128 + t];
        Svec[t] = sv;
    }
    __syncthreads();
    if (t < 128) {
        float Csum = (red4[0] + red4[1]) + (red4[2] + red4[3]);
        float acc = Csum * b2[t];
        for (int j = 0; j < 128; ++j)
            acc = fmaf(Svec[j], W2[j * 128 + t], acc);
        out[g * 128 + t] = acc * (1.0f / 256.0f);
    }
}

extern "C" void kernel_launch(void* const* d_in, const int* in_sizes, int n_in,
                              void* d_out, int out_size, void* d_ws, size_t ws_size,
                              hipStream_t stream) {
    const float* x  = (const float*)d_in[0];
    const float* W1 = (const float*)d_in[2];   // node_w1 [16][128]
    const float* b1 = (const float*)d_in[3];   // node_b1 [128]
    const float* W2 = (const float*)d_in[4];   // node_w2 [128][128]
    const float* b2 = (const float*)d_in[5];   // node_b2 [128]
    const float* pw = (const float*)d_in[22];  // pool_w  [3][128]
    float* out = (float*)d_out;

    float4* d4 = (float4*)d_ws;   // [65536] float4 = 1 MB

    k1_fused<<<256, 256, 0, stream>>>(x, W1, b1, W2, b2, pw, d4);
    k2_cascade<<<NGRAPH, 1024, 0, stream>>>(x, W1, b1, W2, b2, d4, out);
}